// Round 7
// baseline (262.615 us; speedup 1.0000x reference)
//
#include <hip/hip_runtime.h>
#include <hip/hip_bf16.h>

#define A_DIM 1024
#define B_DIM 16
#define DM    512
#define NH    8
#define HD    64
#define NTOK  (A_DIM * B_DIM)

#define LDT 72   // padded LDS leading dim (shorts); 144 B rows (16B-aligned)
#define LOG2E 1.44269504088896f

typedef short s16x8 __attribute__((ext_vector_type(8)));   // 8 bf16, MFMA A/B frag
typedef short s16x4 __attribute__((ext_vector_type(4)));
typedef float f32x4 __attribute__((ext_vector_type(4)));   // MFMA C/D frag

static __device__ __forceinline__ unsigned short f2b(float f) {
    __hip_bfloat16 h = __float2bfloat16(f);
    unsigned short u;
    __builtin_memcpy(&u, &h, 2);
    return u;
}
// packed f32 pair -> bf16x2 in one uint (v_cvt_pk)
static __device__ __forceinline__ unsigned int pk2(float a, float b) {
    __hip_bfloat162 h = __float22bfloat162_rn(make_float2(a, b));
    unsigned int u;
    __builtin_memcpy(&u, &h, 4);
    return u;
}
// packed f32x4 -> bf16x4
static __device__ __forceinline__ uint2 cvt4(float4 v) {
    return make_uint2(pk2(v.x, v.y), pk2(v.z, v.w));
}

// ---------------------------------------------------------------------------
// Kernel 0: bias pre-scale (x log2e) so attention softmax uses raw exp2.
// ---------------------------------------------------------------------------
__global__ __launch_bounds__(256) void bias_scale(
    const float* __restrict__ in, float* __restrict__ out)
{
    int i = (blockIdx.x * 256 + threadIdx.x) * 4;
    float4 v = *(const float4*)&in[i];
    v.x *= LOG2E; v.y *= LOG2E; v.z *= LOG2E; v.w *= LOG2E;
    *(float4*)&out[i] = v;
}

// ---------------------------------------------------------------------------
// Kernel 1: fused QKV projection.  Q pre-scaled by HD^-0.5 * log2e.
// ---------------------------------------------------------------------------
__global__ __launch_bounds__(256) void qkv_gemm(
    const float* __restrict__ src,
    const float* __restrict__ Wq, const float* __restrict__ bq,
    const float* __restrict__ Wk, const float* __restrict__ bk,
    const float* __restrict__ Wv, const float* __restrict__ bv,
    short* __restrict__ Qb, short* __restrict__ Kb, short* __restrict__ Vb)
{
    __shared__ short As[128 * LDT];
    __shared__ short Bs[128 * LDT];

    const int tid  = threadIdx.x;
    const int wave = tid >> 6, lane = tid & 63;
    const int quad = lane >> 4, l16 = lane & 15;
    const int waveM = (wave >> 1) * 64, waveN = (wave & 1) * 64;
    const int mbase = blockIdx.y * 128;
    const int nbase = blockIdx.x * 128;          // 0..1535
    const int mat   = nbase >> 9;                // 0:Q 1:K 2:V
    const float* W    = (mat == 0) ? Wq : (mat == 1) ? Wk : Wv;
    const float* bvec = (mat == 0) ? bq : (mat == 1) ? bk : bv;
    short* dst        = (mat == 0) ? Qb : (mat == 1) ? Kb : Vb;
    const float oscale = (mat == 0) ? 0.125f * LOG2E : 1.0f;
    const int wrow0 = nbase & 511;

    f32x4 acc[4][4];
    #pragma unroll
    for (int i = 0; i < 4; i++)
        #pragma unroll
        for (int j = 0; j < 4; j++)
            acc[i][j] = (f32x4){0.f, 0.f, 0.f, 0.f};

    for (int kb = 0; kb < 8; ++kb) {
        __syncthreads();
        #pragma unroll
        for (int p = 0; p < 8; p++) {
            int chunk = tid + p * 256;
            int row = chunk >> 4, c = chunk & 15;
            float4 a4 = *(const float4*)&src[(mbase + row) * 512 + kb * 64 + c * 4];
            *(uint2*)&As[row * LDT + c * 4] = cvt4(a4);
            float4 w4 = *(const float4*)&W[(wrow0 + row) * 512 + kb * 64 + c * 4];
            *(uint2*)&Bs[row * LDT + c * 4] = cvt4(w4);
        }
        __syncthreads();
        #pragma unroll
        for (int k0i = 0; k0i < 2; k0i++) {
            s16x8 af[4], bf[4];
            #pragma unroll
            for (int mi = 0; mi < 4; mi++)
                af[mi] = *(const s16x8*)&As[(waveM + mi * 16 + l16) * LDT + (k0i * 4 + quad) * 8];
            #pragma unroll
            for (int ni = 0; ni < 4; ni++)
                bf[ni] = *(const s16x8*)&Bs[(waveN + ni * 16 + l16) * LDT + (k0i * 4 + quad) * 8];
            #pragma unroll
            for (int mi = 0; mi < 4; mi++)
                #pragma unroll
                for (int ni = 0; ni < 4; ni++)
                    acc[mi][ni] = __builtin_amdgcn_mfma_f32_16x16x32_bf16(
                        af[mi], bf[ni], acc[mi][ni], 0, 0, 0);
        }
    }

    #pragma unroll
    for (int mi = 0; mi < 4; mi++) {
        #pragma unroll
        for (int ni = 0; ni < 4; ni++) {
            #pragma unroll
            for (int r = 0; r < 4; r++) {
                int t = mbase + waveM + mi * 16 + quad * 4 + r;       // token = a*16+b
                int o = wrow0 + waveN + ni * 16 + l16;                // col in [0,512)
                float v = (acc[mi][ni][r] + bvec[o]) * oscale;
                int a = t >> 4, bb = t & 15, n = o >> 6, d = o & 63;
                dst[((bb * NH + n) * A_DIM + a) * HD + d] = (short)f2b(v);
            }
        }
    }
}

// ---------------------------------------------------------------------------
// Kernel 2: flash attention (S^T formulation).  One wg per (b*nh, 64 q-rows).
// S^T = K*Q^T so P exits the MFMA already in A-fragment layout (per-lane:
// q = l16, keys = quad*4+r) -> no P LDS round-trip.  Bias loads are float4.
// K/Vt tiles double-buffered; one barrier per k-tile.
// ---------------------------------------------------------------------------
__global__ __launch_bounds__(256) void attn_kernel(
    const short* __restrict__ Qb, const short* __restrict__ Kb,
    const short* __restrict__ Vb, const float* __restrict__ biasS,
    short* __restrict__ AO)
{
    __shared__ short Ks[2][64 * LDT];
    __shared__ short Vt[2][64 * LDT];   // Vt[d][k] chunk-swizzled (see store)

    const int tid  = threadIdx.x;
    const int lane = tid & 63;
    const int wave = tid >> 6;
    const int quad = lane >> 4, l16 = lane & 15;
    const int qh = quad >> 1, ql = quad & 1;
    const int bn = blockIdx.y;                       // b*8 + n
    const int qrow0 = blockIdx.x * 64 + wave * 16;   // this wave's first q row

    const short* Qg = Qb + bn * (A_DIM * HD);
    const short* Kg = Kb + bn * (A_DIM * HD);
    const short* Vg = Vb + bn * (A_DIM * HD);
    const float* brow = biasS + (size_t)(qrow0 + l16) * A_DIM;

    // Q fragments (B-operand layout): B[n=q=l16][k=k0i*32+quad*8+j]
    s16x8 qf[2];
    #pragma unroll
    for (int k0i = 0; k0i < 2; k0i++)
        qf[k0i] = *(const s16x8*)&Qg[(qrow0 + l16) * HD + k0i * 32 + quad * 8];

    // staging geometry (kb-invariant)
    const int row0 = tid >> 3, c0 = tid & 7;          // chunk p=0
    const int row1 = (tid + 256) >> 3, c1 = c0;       // chunk p=1 (c identical)

    float lsum = 0.f;
    f32x4 of[4];
    #pragma unroll
    for (int db = 0; db < 4; db++) of[db] = (f32x4){0.f, 0.f, 0.f, 0.f};

    // preload tile 0 into buffer 0
    {
        s16x8 k0 = *(const s16x8*)&Kg[row0 * HD + c0 * 8];
        s16x8 k1 = *(const s16x8*)&Kg[row1 * HD + c1 * 8];
        s16x8 v0 = *(const s16x8*)&Vg[row0 * HD + c0 * 8];
        s16x8 v1 = *(const s16x8*)&Vg[row1 * HD + c1 * 8];
        *(s16x8*)&Ks[0][row0 * LDT + c0 * 8] = k0;
        *(s16x8*)&Ks[0][row1 * LDT + c1 * 8] = k1;
        #pragma unroll
        for (int j = 0; j < 8; j++) {
            Vt[0][(c0 * 8 + j) * LDT + (((row0 >> 3) ^ c0) << 3) + (row0 & 7)] = v0[j];
            Vt[0][(c1 * 8 + j) * LDT + (((row1 >> 3) ^ c1) << 3) + (row1 & 7)] = v1[j];
        }
    }
    __syncthreads();

    for (int kb = 0; kb < 16; ++kb) {
        const int buf = kb & 1;

        // prefetch next tile into registers (overlaps compute)
        s16x8 kp0, kp1, vp0, vp1;
        if (kb < 15) {
            const short* Kn = Kg + (kb + 1) * 64 * HD;
            const short* Vn = Vg + (kb + 1) * 64 * HD;
            kp0 = *(const s16x8*)&Kn[row0 * HD + c0 * 8];
            kp1 = *(const s16x8*)&Kn[row1 * HD + c1 * 8];
            vp0 = *(const s16x8*)&Vn[row0 * HD + c0 * 8];
            vp1 = *(const s16x8*)&Vn[row1 * HD + c1 * 8];
        }

        // S^T = K Q^T : D[m=key][n=q]; C-layout: col=l16=q, row=quad*4+r=key
        float pv[4][4];
        #pragma unroll
        for (int cb = 0; cb < 4; cb++) {
            f32x4 s = (f32x4){0.f, 0.f, 0.f, 0.f};
            #pragma unroll
            for (int k0i = 0; k0i < 2; k0i++) {
                s16x8 kf = *(const s16x8*)&Ks[buf][(cb * 16 + l16) * LDT + (k0i * 4 + quad) * 8];
                s = __builtin_amdgcn_mfma_f32_16x16x32_bf16(kf, qf[k0i], s, 0, 0, 0);
            }
            float4 bz = *(const float4*)&brow[kb * 64 + cb * 16 + quad * 4];
            pv[cb][0] = __builtin_exp2f(s[0] + bz.x);
            pv[cb][1] = __builtin_exp2f(s[1] + bz.y);
            pv[cb][2] = __builtin_exp2f(s[2] + bz.z);
            pv[cb][3] = __builtin_exp2f(s[3] + bz.w);
            lsum += pv[cb][0] + pv[cb][1] + pv[cb][2] + pv[cb][3];
        }

        // P fragments: A[m=q=l16][k-slot j]; j=0..3 -> cb even, j=4..7 -> cb odd
        uint4 ua = make_uint4(pk2(pv[0][0], pv[0][1]), pk2(pv[0][2], pv[0][3]),
                              pk2(pv[1][0], pv[1][1]), pk2(pv[1][2], pv[1][3]));
        uint4 ub = make_uint4(pk2(pv[2][0], pv[2][1]), pk2(pv[2][2], pv[2][3]),
                              pk2(pv[3][0], pv[3][1]), pk2(pv[3][2], pv[3][3]));
        s16x8 pfA, pfB;
        __builtin_memcpy(&pfA, &ua, 16);
        __builtin_memcpy(&pfB, &ub, 16);

        // O += P V : B[n=d][k-slot] from swizzled Vt; same k-space permutation
        #pragma unroll
        for (int db = 0; db < 4; db++) {
            int dd = db * 16 + l16, d3 = dd >> 3;
            int base = dd * LDT + ql * 4;
            s16x4 v0 = *(const s16x4*)&Vt[buf][base + (((0 + qh) ^ d3) << 3)];
            s16x4 v1 = *(const s16x4*)&Vt[buf][base + (((2 + qh) ^ d3) << 3)];
            s16x8 vf01 = __builtin_shufflevector(v0, v1, 0, 1, 2, 3, 4, 5, 6, 7);
            of[db] = __builtin_amdgcn_mfma_f32_16x16x32_bf16(pfA, vf01, of[db], 0, 0, 0);
            s16x4 v2 = *(const s16x4*)&Vt[buf][base + (((4 + qh) ^ d3) << 3)];
            s16x4 v3 = *(const s16x4*)&Vt[buf][base + (((6 + qh) ^ d3) << 3)];
            s16x8 vf23 = __builtin_shufflevector(v2, v3, 0, 1, 2, 3, 4, 5, 6, 7);
            of[db] = __builtin_amdgcn_mfma_f32_16x16x32_bf16(pfB, vf23, of[db], 0, 0, 0);
        }

        // stage prefetched tile into the other buffer
        if (kb < 15) {
            const int nb = buf ^ 1;
            *(s16x8*)&Ks[nb][row0 * LDT + c0 * 8] = kp0;
            *(s16x8*)&Ks[nb][row1 * LDT + c1 * 8] = kp1;
            #pragma unroll
            for (int j = 0; j < 8; j++) {
                Vt[nb][(c0 * 8 + j) * LDT + (((row0 >> 3) ^ c0) << 3) + (row0 & 7)] = vp0[j];
                Vt[nb][(c1 * 8 + j) * LDT + (((row1 >> 3) ^ c1) << 3) + (row1 & 7)] = vp1[j];
            }
        }
        __syncthreads();
    }

    // full row-sum for q=l16: reduce across quads, then fetch per-r values
    lsum += __shfl_xor(lsum, 16);
    lsum += __shfl_xor(lsum, 32);
    float linv[4];
    #pragma unroll
    for (int r = 0; r < 4; r++)
        linv[r] = 1.0f / __shfl(lsum, (lane & 48) | (quad * 4 + r));

    // epilogue: of[db] C-layout: col=l16=d, row=quad*4+r=q -> [A][B][DM]
    const int b = bn >> 3, n = bn & 7;
    #pragma unroll
    for (int db = 0; db < 4; db++) {
        #pragma unroll
        for (int r = 0; r < 4; r++) {
            int a = qrow0 + quad * 4 + r;
            int d = db * 16 + l16;
            AO[(a * B_DIM + b) * DM + n * HD + d] = (short)f2b(of[db][r] * linv[r]);
        }
    }
}

// ---------------------------------------------------------------------------
// Kernel 3: output projection.
// ---------------------------------------------------------------------------
__global__ __launch_bounds__(256) void out_gemm(
    const short* __restrict__ Xin,
    const float* __restrict__ Wo, const float* __restrict__ bo,
    float* __restrict__ out)
{
    __shared__ short As[128 * LDT];
    __shared__ short Bs[128 * LDT];

    const int tid  = threadIdx.x;
    const int wave = tid >> 6, lane = tid & 63;
    const int quad = lane >> 4, l16 = lane & 15;
    const int waveM = (wave >> 1) * 64, waveN = (wave & 1) * 64;
    const int mbase = blockIdx.y * 128;
    const int nbase = blockIdx.x * 128;   // 0..511

    f32x4 acc[4][4];
    #pragma unroll
    for (int i = 0; i < 4; i++)
        #pragma unroll
        for (int j = 0; j < 4; j++)
            acc[i][j] = (f32x4){0.f, 0.f, 0.f, 0.f};

    for (int kb = 0; kb < 8; ++kb) {
        __syncthreads();
        #pragma unroll
        for (int p = 0; p < 4; p++) {
            int chunk = tid + p * 256;
            int row = chunk >> 3, c = chunk & 7;
            *(s16x8*)&As[row * LDT + c * 8] =
                *(const s16x8*)&Xin[(mbase + row) * 512 + kb * 64 + c * 8];
        }
        #pragma unroll
        for (int p = 0; p < 8; p++) {
            int chunk = tid + p * 256;
            int row = chunk >> 4, c = chunk & 15;
            float4 w4 = *(const float4*)&Wo[(nbase + row) * 512 + kb * 64 + c * 4];
            *(uint2*)&Bs[row * LDT + c * 4] = cvt4(w4);
        }
        __syncthreads();
        #pragma unroll
        for (int k0i = 0; k0i < 2; k0i++) {
            s16x8 af[4], bf[4];
            #pragma unroll
            for (int mi = 0; mi < 4; mi++)
                af[mi] = *(const s16x8*)&As[(waveM + mi * 16 + l16) * LDT + (k0i * 4 + quad) * 8];
            #pragma unroll
            for (int ni = 0; ni < 4; ni++)
                bf[ni] = *(const s16x8*)&Bs[(waveN + ni * 16 + l16) * LDT + (k0i * 4 + quad) * 8];
            #pragma unroll
            for (int mi = 0; mi < 4; mi++)
                #pragma unroll
                for (int ni = 0; ni < 4; ni++)
                    acc[mi][ni] = __builtin_amdgcn_mfma_f32_16x16x32_bf16(
                        af[mi], bf[ni], acc[mi][ni], 0, 0, 0);
        }
    }

    #pragma unroll
    for (int mi = 0; mi < 4; mi++) {
        #pragma unroll
        for (int ni = 0; ni < 4; ni++) {
            #pragma unroll
            for (int r = 0; r < 4; r++) {
                int t = mbase + waveM + mi * 16 + quad * 4 + r;
                int o = nbase + waveN + ni * 16 + l16;
                out[t * 512 + o] = acc[mi][ni][r] + bo[o];
            }
        }
    }
}

// ---------------------------------------------------------------------------
extern "C" void kernel_launch(void* const* d_in, const int* in_sizes, int n_in,
                              void* d_out, int out_size, void* d_ws, size_t ws_size,
                              hipStream_t stream) {
    const float* src  = (const float*)d_in[0];
    const float* bias = (const float*)d_in[1];
    const float* Wq   = (const float*)d_in[2];
    const float* bq   = (const float*)d_in[3];
    const float* Wk   = (const float*)d_in[4];
    const float* bk   = (const float*)d_in[5];
    const float* Wv   = (const float*)d_in[6];
    const float* bv   = (const float*)d_in[7];
    const float* Wo   = (const float*)d_in[8];
    const float* bo   = (const float*)d_in[9];

    short* ws = (short*)d_ws;
    short* Qb = ws;                        // 16 MB (Q pre-scaled)
    short* Kb = ws + (size_t)(1 << 23);    // 16 MB
    short* Vb = ws + (size_t)(2 << 23);    // 16 MB  (ws base usage: 48 MB)

    const bool big_ws = ws_size >= (size_t)(72u << 20);
    float* biasS;
    short* AO;
    if (big_ws) {
        biasS = (float*)(ws + (size_t)3 * (1 << 23));            // 4 MB
        AO    = ws + (size_t)3 * (1 << 23) + (size_t)(1 << 21);  // 16 MB
    } else {
        AO    = (short*)d_out;                                   // [0, 16.8 MB)
        biasS = (float*)((short*)d_out + (size_t)NTOK * DM);     // next 4 MB
    }

    bias_scale<<<dim3(A_DIM * A_DIM / 1024), 256, 0, stream>>>(bias, biasS);
    qkv_gemm<<<dim3(12, 128), 256, 0, stream>>>(src, Wq, bq, Wk, bk, Wv, bv, Qb, Kb, Vb);
    attn_kernel<<<dim3(16, 128), 256, 0, stream>>>(Qb, Kb, Vb, biasS, AO);

    if (big_ws) {
        out_gemm<<<dim3(4, 128), 256, 0, stream>>>(AO, Wo, bo, (float*)d_out);
    } else {
        float* Cs = (float*)d_ws;          // over dead Q+K regions (32 MB)
        out_gemm<<<dim3(4, 128), 256, 0, stream>>>(AO, Wo, bo, Cs);
        (void)hipMemcpyAsync(d_out, Cs, (size_t)out_size * sizeof(float),
                             hipMemcpyDeviceToDevice, stream);
    }
}